// Round 1
// baseline (737.930 us; speedup 1.0000x reference)
//
#include <hip/hip_runtime.h>
#include <hip/hip_bf16.h>
#include <cstdint>
#include <cstddef>

// ---------------------------------------------------------------------------
// SelfAttention (B=2, S=4096, H=2048, fp32 in/out), fp16 MFMA internally.
//   q = X Wq^T + bq ; k = X Wk^T + bk ; v = X Wv^T + bv
//   out = softmax(q k^T) v
// Stages: cvt->fp16 | 3x proj GEMM | QK^T GEMM (fp32 S) | row softmax | PV GEMM
// All GEMMs share one 128x128-tile B^T-layout kernel (A[M,K], B[N,K] row-major),
// m97-style: global_load_lds 16B staging, BK=64, 4 waves, 4x4 16x16x32 frags.
// Workspace (aliased lifetimes): 224 MB total.
// ---------------------------------------------------------------------------

typedef _Float16 half8 __attribute__((ext_vector_type(8)));
typedef _Float16 half4 __attribute__((ext_vector_type(4)));
typedef float    f32x4 __attribute__((ext_vector_type(4)));

__device__ __forceinline__ void gld_lds16(const void* g, void* l) {
  // async 16B/lane global->LDS. LDS dest is wave-uniform base + lane*16.
  __builtin_amdgcn_global_load_lds(
      (const __attribute__((address_space(1))) unsigned int*)g,
      (__attribute__((address_space(3))) unsigned int*)l,
      16, 0, 0);
}

// MODE 0: fp32 row-major out, no bias    (scores, final out)
// MODE 1: fp16 row-major out + bias      (Q, K projections)
// MODE 2: fp16 TRANSPOSED out + bias     (V projection -> Vt[col*ldo + row])
template <int MODE>
__global__ __launch_bounds__(256) void gemm_bt(
    const _Float16* __restrict__ A, int lda,
    const _Float16* __restrict__ B, int ldb,
    const float* __restrict__ bias,
    void* __restrict__ out, int ldo, int K,
    size_t sA, size_t sB, size_t sO)
{
  __shared__ _Float16 lA[128 * 64];
  __shared__ _Float16 lB[128 * 64];

  const int tid  = threadIdx.x;
  const int wave = tid >> 6;
  const int lane = tid & 63;
  const int bm = blockIdx.x * 128;
  const int bn = blockIdx.y * 128;
  A += (size_t)blockIdx.z * sA;
  B += (size_t)blockIdx.z * sB;

  const int wm = wave >> 1;        // 2x2 wave grid, each wave owns 64x64
  const int wn = wave & 1;
  const int lr = lane >> 3;        // staging: row within 8-row chunk
  const int lc = (lane & 7) * 8;   // staging: halves offset within row
  const int kg = (lane >> 4) * 8;  // frag: k-group base
  const int fr = lane & 15;        // frag: row (A) / col (B)

  f32x4 acc[4][4];
  const f32x4 zero = {0.f, 0.f, 0.f, 0.f};
#pragma unroll
  for (int mi = 0; mi < 4; ++mi)
#pragma unroll
    for (int ni = 0; ni < 4; ++ni) acc[mi][ni] = zero;

  for (int kk = 0; kk < K; kk += 64) {
    __syncthreads();  // previous compute done -> LDS reusable
#pragma unroll
    for (int i = 0; i < 4; ++i) {
      const int c = i * 4 + wave;          // chunk 0..15 (8 rows, 1KB each)
      const int row = c * 8 + lr;
      gld_lds16(A + (size_t)(bm + row) * lda + kk + lc, lA + c * 512);
      gld_lds16(B + (size_t)(bn + row) * ldb + kk + lc, lB + c * 512);
    }
    __syncthreads();  // barrier drains vmcnt(0): staged data visible
#pragma unroll
    for (int ks = 0; ks < 2; ++ks) {
      half8 af[4], bf[4];
#pragma unroll
      for (int mi = 0; mi < 4; ++mi)
        af[mi] = *(const half8*)&lA[(wm * 64 + mi * 16 + fr) * 64 + ks * 32 + kg];
#pragma unroll
      for (int ni = 0; ni < 4; ++ni)
        bf[ni] = *(const half8*)&lB[(wn * 64 + ni * 16 + fr) * 64 + ks * 32 + kg];
#pragma unroll
      for (int mi = 0; mi < 4; ++mi)
#pragma unroll
        for (int ni = 0; ni < 4; ++ni)
          acc[mi][ni] = __builtin_amdgcn_mfma_f32_16x16x32_f16(
              af[mi], bf[ni], acc[mi][ni], 0, 0, 0);
    }
  }

  // Epilogue. C/D frag: col = lane&15, rows = (lane>>4)*4 + j (verified m89/m91).
#pragma unroll
  for (int mi = 0; mi < 4; ++mi) {
#pragma unroll
    for (int ni = 0; ni < 4; ++ni) {
      const int col  = bn + wn * 64 + ni * 16 + (lane & 15);
      const int row0 = bm + wm * 64 + mi * 16 + ((lane >> 4) << 2);
      const f32x4 a = acc[mi][ni];
      if constexpr (MODE == 0) {
        float* O = (float*)out + (size_t)blockIdx.z * sO;
#pragma unroll
        for (int j = 0; j < 4; ++j) O[(size_t)(row0 + j) * ldo + col] = a[j];
      } else if constexpr (MODE == 1) {
        _Float16* O = (_Float16*)out;
        const float bb = bias[col];
#pragma unroll
        for (int j = 0; j < 4; ++j)
          O[(size_t)(row0 + j) * ldo + col] = (_Float16)(a[j] + bb);
      } else {  // MODE 2: transposed store, 4 consecutive rows -> one 8B store
        _Float16* O = (_Float16*)out;
        const float bb = bias[col];
        half4 h;
#pragma unroll
        for (int j = 0; j < 4; ++j) h[j] = (_Float16)(a[j] + bb);
        *(half4*)(O + (size_t)col * ldo + row0) = h;
      }
    }
  }
}

__device__ __forceinline__ float wave_max_f(float v) {
#pragma unroll
  for (int o = 32; o; o >>= 1) v = fmaxf(v, __shfl_xor(v, o));
  return v;
}
__device__ __forceinline__ float wave_sum_f(float v) {
#pragma unroll
  for (int o = 32; o; o >>= 1) v += __shfl_xor(v, o);
  return v;
}

// one 256-thread block per row of 4096 fp32 scores -> fp16 probabilities
__global__ __launch_bounds__(256) void softmax_rows(
    const float* __restrict__ S, _Float16* __restrict__ P)
{
  __shared__ float rmax[4], rsum[4];
  const int tid = threadIdx.x;
  const float* s = S + (size_t)blockIdx.x * 4096;
  _Float16*    p = P + (size_t)blockIdx.x * 4096;

  f32x4 v[4];
  float m = -3.0e38f;
#pragma unroll
  for (int i = 0; i < 4; ++i) {
    v[i] = ((const f32x4*)s)[i * 256 + tid];
#pragma unroll
    for (int j = 0; j < 4; ++j) m = fmaxf(m, v[i][j]);
  }
  m = wave_max_f(m);
  if ((tid & 63) == 0) rmax[tid >> 6] = m;
  __syncthreads();
  m = fmaxf(fmaxf(rmax[0], rmax[1]), fmaxf(rmax[2], rmax[3]));

  float e[16];
  float sum = 0.f;
#pragma unroll
  for (int i = 0; i < 4; ++i)
#pragma unroll
    for (int j = 0; j < 4; ++j) {
      const float t = __expf(v[i][j] - m);
      e[i * 4 + j] = t;
      sum += t;
    }
  sum = wave_sum_f(sum);
  if ((tid & 63) == 0) rsum[tid >> 6] = sum;
  __syncthreads();
  sum = rsum[0] + rsum[1] + rsum[2] + rsum[3];
  const float inv = 1.0f / sum;

#pragma unroll
  for (int i = 0; i < 4; ++i) {
    half4 h;
#pragma unroll
    for (int j = 0; j < 4; ++j) h[j] = (_Float16)(e[i * 4 + j] * inv);
    ((half4*)p)[i * 256 + tid] = h;
  }
}

__global__ __launch_bounds__(256) void cvt_f32_f16(
    const float* __restrict__ in, _Float16* __restrict__ out, int n4)
{
  const int stride = gridDim.x * 256;
  for (int idx = blockIdx.x * 256 + threadIdx.x; idx < n4; idx += stride) {
    const f32x4 x = ((const f32x4*)in)[idx];
    half4 h;
#pragma unroll
    for (int j = 0; j < 4; ++j) h[j] = (_Float16)x[j];
    ((half4*)out)[idx] = h;
  }
}

extern "C" void kernel_launch(void* const* d_in, const int* in_sizes, int n_in,
                              void* d_out, int out_size, void* d_ws, size_t ws_size,
                              hipStream_t stream)
{
  const float* X  = (const float*)d_in[0];
  const float* Wq = (const float*)d_in[1];
  const float* bq = (const float*)d_in[2];
  const float* Wk = (const float*)d_in[3];
  const float* bk = (const float*)d_in[4];
  const float* Wv = (const float*)d_in[5];
  const float* bv = (const float*)d_in[6];
  float* out = (float*)d_out;

  const size_t NX = (size_t)2 * 4096 * 2048;  // 16,777,216
  const size_t NW = (size_t)2048 * 2048;      //  4,194,304
  const size_t NS = (size_t)2 * 4096 * 4096;  // 33,554,432

  // Workspace layout (lifetime-aliased, total 224 MB):
  //  [0, 134.2MB)        : S fp32      — also hosts Xh(33.5) + Wq/Wk/Wv fp16 (25.2)
  //                        during stage 1-2 (dead before S is written)
  //  [134.2MB, 201.3MB)  : Q fp16 | Kp fp16 — later aliased by P fp16 (67MB)
  //  [201.3MB, 234.9MB)  : Vt fp16 [2048][8192]
  char* w = (char*)d_ws;
  float*    Ssc = (float*)w;
  _Float16* Xh  = (_Float16*)w;
  _Float16* Wqh = (_Float16*)(w + NX * 2);
  _Float16* Wkh = (_Float16*)(w + NX * 2 + NW * 2);
  _Float16* Wvh = (_Float16*)(w + NX * 2 + 2 * NW * 2);
  _Float16* Q   = (_Float16*)(w + NS * 4);
  _Float16* Kp  = (_Float16*)(w + NS * 4 + NX * 2);
  _Float16* P   = (_Float16*)(w + NS * 4);            // aliases Q+Kp
  _Float16* Vt  = (_Float16*)(w + NS * 4 + 2 * NX * 2);

  // 1) fp32 -> fp16 conversions
  cvt_f32_f16<<<2048, 256, 0, stream>>>(X,  Xh,  (int)(NX / 4));
  cvt_f32_f16<<<512,  256, 0, stream>>>(Wq, Wqh, (int)(NW / 4));
  cvt_f32_f16<<<512,  256, 0, stream>>>(Wk, Wkh, (int)(NW / 4));
  cvt_f32_f16<<<512,  256, 0, stream>>>(Wv, Wvh, (int)(NW / 4));

  const dim3 blk(256);
  // 2) projections: [8192,2048] = Xh[8192,2048] @ W[2048,2048]^T + b
  gemm_bt<1><<<dim3(64, 16, 1), blk, 0, stream>>>(Xh, 2048, Wqh, 2048, bq,
                                                  Q, 2048, 2048, 0, 0, 0);
  gemm_bt<1><<<dim3(64, 16, 1), blk, 0, stream>>>(Xh, 2048, Wkh, 2048, bk,
                                                  Kp, 2048, 2048, 0, 0, 0);
  gemm_bt<2><<<dim3(64, 16, 1), blk, 0, stream>>>(Xh, 2048, Wvh, 2048, bv,
                                                  Vt, 8192, 2048, 0, 0, 0);
  // 3) scores: per batch, S[4096,4096] = Q K^T (fp32 out)
  gemm_bt<0><<<dim3(32, 32, 2), blk, 0, stream>>>(
      Q, 2048, Kp, 2048, nullptr, Ssc, 4096, 2048,
      (size_t)4096 * 2048, (size_t)4096 * 2048, (size_t)4096 * 4096);
  // 4) row softmax (8192 rows), fp32 -> fp16 probs
  softmax_rows<<<8192, 256, 0, stream>>>(Ssc, P);
  // 5) out: per batch, [4096,2048] = P[4096,4096] @ Vt^T (Vt rows = h, ldb=8192)
  gemm_bt<0><<<dim3(32, 16, 2), blk, 0, stream>>>(
      P, 4096, Vt, 8192, nullptr, out, 2048, 4096,
      (size_t)4096 * 4096, (size_t)4096, (size_t)4096 * 2048);
}

// Round 2
// 510.182 us; speedup vs baseline: 1.4464x; 1.4464x over previous
//
#include <hip/hip_runtime.h>
#include <hip/hip_bf16.h>
#include <cstdint>
#include <cstddef>

// ---------------------------------------------------------------------------
// SelfAttention (B=2, S=4096, H=2048, fp32 in/out), fp16 MFMA internally.
// Round 2: all GEMMs use the 256x256-tile 8-phase schedule (T2+T3+T4+T5):
//   - 8 waves (512 thr), per-wave 128x64 output, BK=64, 2 K-tiles/iter
//   - LDS 128KB: A/B x dbuf x 2 halves of [128 rows][64 halfs] (16KB regions)
//   - XOR swizzle (row&7)<<4 on LDS column bytes; staging keeps LDS linear
//     and pre-swizzles the GLOBAL source column (both-sides rule, m173/m201)
//   - 1 half-tile staged per phase via global_load_lds x2; counted vmcnt(2)
//     only at phases 4 and 8; raw s_barrier; setprio around MFMA clusters
// ---------------------------------------------------------------------------

typedef _Float16 half8 __attribute__((ext_vector_type(8)));
typedef _Float16 half4 __attribute__((ext_vector_type(4)));
typedef float    f32x4 __attribute__((ext_vector_type(4)));

__device__ __forceinline__ void gld_lds16(const void* g, void* l) {
  __builtin_amdgcn_global_load_lds(
      (const __attribute__((address_space(1))) unsigned int*)g,
      (__attribute__((address_space(3))) unsigned int*)l, 16, 0, 0);
}

#define FENCE()  asm volatile("" ::: "memory")
#define LGKM(n)  asm volatile("s_waitcnt lgkmcnt(" #n ")" ::: "memory")
#define VMC(n)   asm volatile("s_waitcnt vmcnt(" #n ")" ::: "memory")
#define SBAR()   do { __builtin_amdgcn_s_barrier(); FENCE(); } while (0)
#define SCHED0() __builtin_amdgcn_sched_barrier(0)
#define PRIO1()  __builtin_amdgcn_s_setprio(1)
#define PRIO0()  __builtin_amdgcn_s_setprio(0)

// ds-load one A register subtile (4 m-frags x 2 k-slices = 8 x ds_read_b128)
#define LOAD_A(bsel, mh)                                                     \
  {                                                                          \
    const char* _p = ldsA + ((bsel)*2 + wr) * 16384 + fr * 128;              \
    _Pragma("unroll") for (int mi = 0; mi < 4; ++mi) {                       \
      af[mi][0] = *(const half8*)(_p + ((mh)*4 + mi) * 2048 + cS0);          \
      af[mi][1] = *(const half8*)(_p + ((mh)*4 + mi) * 2048 + cS1);          \
    }                                                                        \
  }

// ds-load one B register subtile (2 n-frags x 2 k-slices = 4 x ds_read_b128)
#define LOAD_B(bsel, nh)                                                     \
  {                                                                          \
    const char* _p = ldsB + ((bsel)*2 + (wc >> 1)) * 16384 +                 \
                     ((wc & 1) * 64 + fr) * 128;                             \
    _Pragma("unroll") for (int ni = 0; ni < 2; ++ni) {                       \
      bf[ni][0] = *(const half8*)(_p + ((nh)*2 + ni) * 2048 + cS0);          \
      bf[ni][1] = *(const half8*)(_p + ((nh)*2 + ni) * 2048 + cS1);          \
    }                                                                        \
  }

// one C-quadrant x K=64: 16 MFMA
#define MFMA_Q(mh, nh)                                                       \
  _Pragma("unroll") for (int mi = 0; mi < 4; ++mi)                           \
  _Pragma("unroll") for (int ni = 0; ni < 2; ++ni) {                         \
    f32x4& _c = acc[(mh)*4 + mi][(nh)*2 + ni];                               \
    _c = __builtin_amdgcn_mfma_f32_16x16x32_f16(af[mi][0], bf[ni][0], _c, 0, 0, 0); \
    _c = __builtin_amdgcn_mfma_f32_16x16x32_f16(af[mi][1], bf[ni][1], _c, 0, 0, 0); \
  }

// stage one 128x64 half-tile (16KB): per wave 2 x global_load_lds(16B).
// LDS dest linear; global source column pre-swizzled so that reads with
// cb ^ ((row&7)<<4) see the right element (involution, both-sides rule).
#define STAGE_A(bsel, h, t)                                                  \
  {                                                                          \
    const _Float16* _s = A + (size_t)(bm + (h)*128 + wv*16 + lr) * lda +     \
                         (size_t)(t) * 64 + sc8;                             \
    char* _d = ldsA + ((bsel)*2 + (h)) * 16384 + wv * 2048;                  \
    gld_lds16(_s, _d);                                                       \
    gld_lds16(_s + ((size_t)lda << 3), _d + 1024);                           \
  }
#define STAGE_B(bsel, h, t)                                                  \
  {                                                                          \
    const _Float16* _s = B + (size_t)(bn + (h)*128 + wv*16 + lr) * ldb +     \
                         (size_t)(t) * 64 + sc8;                             \
    char* _d = ldsB + ((bsel)*2 + (h)) * 16384 + wv * 2048;                  \
    gld_lds16(_s, _d);                                                       \
    gld_lds16(_s + ((size_t)ldb << 3), _d + 1024);                           \
  }

// MODE 0: fp32 row-major out, no bias   (scores, final out)
// MODE 1: fp16 row-major out + bias     (Q, K projections)
// MODE 2: fp16 TRANSPOSED out + bias    (V projection -> Vt[col*ldo + row])
template <int MODE>
__global__ __launch_bounds__(512) void gemm256(
    const _Float16* __restrict__ A, int lda,
    const _Float16* __restrict__ B, int ldb,
    const float* __restrict__ bias,
    void* __restrict__ out, int ldo, int K,
    size_t sA, size_t sB, size_t sO)
{
  __shared__ __attribute__((aligned(128))) char lds[131072];
  char* ldsA = lds;            // [dbuf*2+half][16KB]
  char* ldsB = lds + 65536;

  const int tid  = threadIdx.x;
  const int wv   = tid >> 6;        // 0..7
  const int lane = tid & 63;
  const int wr = wv >> 2;           // 0..1: wave row  (M, 128 rows each)
  const int wc = wv & 3;            // 0..3: wave col  (N, 64 cols each)
  const int bm = blockIdx.x * 256;
  const int bn = blockIdx.y * 256;
  A += (size_t)blockIdx.z * sA;
  B += (size_t)blockIdx.z * sB;

  // fragment-read indexing
  const int fr = lane & 15;                 // frag row (A) / col (B)
  const int kq = lane >> 4;                 // k-quarter 0..3
  const int sx = (fr & 7) << 4;             // swizzle XOR (bytes 4..6)
  const int cS0 = (kq * 16) ^ sx;           // ks=0 column bytes, swizzled
  const int cS1 = (64 + kq * 16) ^ sx;      // ks=1
  // staging indexing
  const int lr  = lane >> 3;                          // 0..7: row in 8-row chunk
  const int sc8 = ((lane & 7) ^ (lr & 7)) << 3;       // src col (halfs), pre-swz

  f32x4 acc[8][4];
  const f32x4 zf = {0.f, 0.f, 0.f, 0.f};
#pragma unroll
  for (int mi = 0; mi < 8; ++mi)
#pragma unroll
    for (int ni = 0; ni < 4; ++ni) acc[mi][ni] = zf;
  half8 af[4][2], bf[2][2];

  const int NT = K >> 6;      // 64-wide K-tiles (even: 32 or 64 here)
  const int NI = NT >> 1;

  // prologue: tile0 (buf0, 4 half-tiles) + A-h0 of tile1 (buf1) = 10 loads/wave
  STAGE_A(0, 0, 0); STAGE_A(0, 1, 0); STAGE_B(0, 0, 0); STAGE_B(0, 1, 0);
  STAGE_A(1, 0, 1);
  VMC(2);   // tile0's 8 loads done; tile1's A-h0 still in flight
  SBAR();

  for (int it = 0; it < NI; ++it) {
    const int t1 = 2 * it + 1, t2 = t1 + 1, t3 = t1 + 2;
    const bool p2 = (t2 < NT), p3 = (t3 < NT);

    // ===== group 1: buf0, K-tile 2it =====
    // ph1 (mh0,nh0)
    LOAD_A(0, 0); LOAD_B(0, 0);
    STAGE_A(1, 1, t1);
    LGKM(8);
    SBAR(); LGKM(0); SCHED0();
    PRIO1(); MFMA_Q(0, 0); PRIO0();
    SBAR();
    // ph2 (mh0,nh1)
    LOAD_B(0, 1);
    STAGE_B(1, 0, t1);
    SBAR(); LGKM(0); SCHED0();
    PRIO1(); MFMA_Q(0, 1); PRIO0();
    SBAR();
    // ph3 (mh1,nh1)
    LOAD_A(0, 1);
    STAGE_B(1, 1, t1);
    SBAR(); LGKM(0); SCHED0();
    PRIO1(); MFMA_Q(1, 1); PRIO0();
    SBAR();
    // ph4 (mh1,nh0)
    LOAD_B(0, 0);
    if (p2) STAGE_A(0, 0, t2);
    SBAR(); LGKM(0); SCHED0();
    PRIO1(); MFMA_Q(1, 0); PRIO0();
    if (p2) { VMC(2); } else { VMC(0); }   // buf1 (t1) fully staged
    SBAR();

    // ===== group 2: buf1, K-tile 2it+1 =====
    // ph5 (mh0,nh0)
    LOAD_A(1, 0); LOAD_B(1, 0);
    if (p2) STAGE_A(0, 1, t2);
    LGKM(8);
    SBAR(); LGKM(0); SCHED0();
    PRIO1(); MFMA_Q(0, 0); PRIO0();
    SBAR();
    // ph6 (mh0,nh1)
    LOAD_B(1, 1);
    if (p2) STAGE_B(0, 0, t2);
    SBAR(); LGKM(0); SCHED0();
    PRIO1(); MFMA_Q(0, 1); PRIO0();
    SBAR();
    // ph7 (mh1,nh1)
    LOAD_A(1, 1);
    if (p2) STAGE_B(0, 1, t2);
    SBAR(); LGKM(0); SCHED0();
    PRIO1(); MFMA_Q(1, 1); PRIO0();
    SBAR();
    // ph8 (mh1,nh0)
    LOAD_B(1, 0);
    if (p3) STAGE_A(1, 0, t3);
    SBAR(); LGKM(0); SCHED0();
    PRIO1(); MFMA_Q(1, 0); PRIO0();
    if (p3) { VMC(2); } else { VMC(0); }   // buf0 (t2) fully staged
    SBAR();
  }

  // epilogue. C/D frag: col = lane&15, rows = (lane>>4)*4 + j
#pragma unroll
  for (int mi = 0; mi < 8; ++mi) {
#pragma unroll
    for (int ni = 0; ni < 4; ++ni) {
      const int col  = bn + wc * 64 + ni * 16 + fr;
      const int row0 = bm + wr * 128 + mi * 16 + kq * 4;
      const f32x4 a = acc[mi][ni];
      if constexpr (MODE == 0) {
        float* O = (float*)out + (size_t)blockIdx.z * sO;
#pragma unroll
        for (int j = 0; j < 4; ++j) O[(size_t)(row0 + j) * ldo + col] = a[j];
      } else if constexpr (MODE == 1) {
        _Float16* O = (_Float16*)out;
        const float bb = bias[col];
#pragma unroll
        for (int j = 0; j < 4; ++j)
          O[(size_t)(row0 + j) * ldo + col] = (_Float16)(a[j] + bb);
      } else {
        _Float16* O = (_Float16*)out;
        const float bb = bias[col];
        half4 h;
#pragma unroll
        for (int j = 0; j < 4; ++j) h[j] = (_Float16)(a[j] + bb);
        *(half4*)(O + (size_t)col * ldo + row0) = h;
      }
    }
  }
}

__device__ __forceinline__ float wave_max_f(float v) {
#pragma unroll
  for (int o = 32; o; o >>= 1) v = fmaxf(v, __shfl_xor(v, o));
  return v;
}
__device__ __forceinline__ float wave_sum_f(float v) {
#pragma unroll
  for (int o = 32; o; o >>= 1) v += __shfl_xor(v, o);
  return v;
}

// one 256-thread block per row of 4096 fp32 scores -> fp16 probabilities
__global__ __launch_bounds__(256) void softmax_rows(
    const float* __restrict__ S, _Float16* __restrict__ P)
{
  __shared__ float rmax[4], rsum[4];
  const int tid = threadIdx.x;
  const float* s = S + (size_t)blockIdx.x * 4096;
  _Float16*    p = P + (size_t)blockIdx.x * 4096;

  f32x4 v[4];
  float m = -3.0e38f;
#pragma unroll
  for (int i = 0; i < 4; ++i) {
    v[i] = ((const f32x4*)s)[i * 256 + tid];
#pragma unroll
    for (int j = 0; j < 4; ++j) m = fmaxf(m, v[i][j]);
  }
  m = wave_max_f(m);
  if ((tid & 63) == 0) rmax[tid >> 6] = m;
  __syncthreads();
  m = fmaxf(fmaxf(rmax[0], rmax[1]), fmaxf(rmax[2], rmax[3]));

  float e[16];
  float sum = 0.f;
#pragma unroll
  for (int i = 0; i < 4; ++i)
#pragma unroll
    for (int j = 0; j < 4; ++j) {
      const float t = __expf(v[i][j] - m);
      e[i * 4 + j] = t;
      sum += t;
    }
  sum = wave_sum_f(sum);
  if ((tid & 63) == 0) rsum[tid >> 6] = sum;
  __syncthreads();
  sum = rsum[0] + rsum[1] + rsum[2] + rsum[3];
  const float inv = 1.0f / sum;

#pragma unroll
  for (int i = 0; i < 4; ++i) {
    half4 h;
#pragma unroll
    for (int j = 0; j < 4; ++j) h[j] = (_Float16)(e[i * 4 + j] * inv);
    ((half4*)p)[i * 256 + tid] = h;
  }
}

__global__ __launch_bounds__(256) void cvt_f32_f16(
    const float* __restrict__ in, _Float16* __restrict__ out, int n4)
{
  const int stride = gridDim.x * 256;
  for (int idx = blockIdx.x * 256 + threadIdx.x; idx < n4; idx += stride) {
    const f32x4 x = ((const f32x4*)in)[idx];
    half4 h;
#pragma unroll
    for (int j = 0; j < 4; ++j) h[j] = (_Float16)x[j];
    ((half4*)out)[idx] = h;
  }
}

extern "C" void kernel_launch(void* const* d_in, const int* in_sizes, int n_in,
                              void* d_out, int out_size, void* d_ws, size_t ws_size,
                              hipStream_t stream)
{
  const float* X  = (const float*)d_in[0];
  const float* Wq = (const float*)d_in[1];
  const float* bq = (const float*)d_in[2];
  const float* Wk = (const float*)d_in[3];
  const float* bk = (const float*)d_in[4];
  const float* Wv = (const float*)d_in[5];
  const float* bv = (const float*)d_in[6];
  float* out = (float*)d_out;

  const size_t NX = (size_t)2 * 4096 * 2048;  // 16,777,216
  const size_t NW = (size_t)2048 * 2048;      //  4,194,304
  const size_t NS = (size_t)2 * 4096 * 4096;  // 33,554,432

  // Workspace layout (lifetime-aliased, total ~235 MB):
  //  [0, 134.2MB)        : S fp32  — also hosts Xh + W*h fp16 during stages 1-2
  //  [134.2MB, 201.3MB)  : Q | Kp fp16 — later aliased by P fp16
  //  [201.3MB, 234.9MB)  : Vt fp16 [2048][8192]
  char* w = (char*)d_ws;
  float*    Ssc = (float*)w;
  _Float16* Xh  = (_Float16*)w;
  _Float16* Wqh = (_Float16*)(w + NX * 2);
  _Float16* Wkh = (_Float16*)(w + NX * 2 + NW * 2);
  _Float16* Wvh = (_Float16*)(w + NX * 2 + 2 * NW * 2);
  _Float16* Q   = (_Float16*)(w + NS * 4);
  _Float16* Kp  = (_Float16*)(w + NS * 4 + NX * 2);
  _Float16* P   = (_Float16*)(w + NS * 4);            // aliases Q+Kp
  _Float16* Vt  = (_Float16*)(w + NS * 4 + 2 * NX * 2);

  // 1) fp32 -> fp16 conversions
  cvt_f32_f16<<<2048, 256, 0, stream>>>(X,  Xh,  (int)(NX / 4));
  cvt_f32_f16<<<512,  256, 0, stream>>>(Wq, Wqh, (int)(NW / 4));
  cvt_f32_f16<<<512,  256, 0, stream>>>(Wk, Wkh, (int)(NW / 4));
  cvt_f32_f16<<<512,  256, 0, stream>>>(Wv, Wvh, (int)(NW / 4));

  const dim3 blk(512);
  // 2) projections: [8192,2048] = Xh[8192,2048] @ W[2048,2048]^T + b
  gemm256<1><<<dim3(32, 8, 1), blk, 0, stream>>>(Xh, 2048, Wqh, 2048, bq,
                                                 Q, 2048, 2048, 0, 0, 0);
  gemm256<1><<<dim3(32, 8, 1), blk, 0, stream>>>(Xh, 2048, Wkh, 2048, bk,
                                                 Kp, 2048, 2048, 0, 0, 0);
  gemm256<2><<<dim3(32, 8, 1), blk, 0, stream>>>(Xh, 2048, Wvh, 2048, bv,
                                                 Vt, 8192, 2048, 0, 0, 0);
  // 3) scores: per batch, S[4096,4096] = Q K^T (fp32 out)
  gemm256<0><<<dim3(16, 16, 2), blk, 0, stream>>>(
      Q, 2048, Kp, 2048, nullptr, Ssc, 4096, 2048,
      (size_t)4096 * 2048, (size_t)4096 * 2048, (size_t)4096 * 4096);
  // 4) row softmax (8192 rows), fp32 -> fp16 probs
  softmax_rows<<<8192, 256, 0, stream>>>(Ssc, P);
  // 5) out: per batch, [4096,2048] = P[4096,4096] @ Vt^T (Vt rows = h)
  gemm256<0><<<dim3(16, 8, 2), blk, 0, stream>>>(
      P, 4096, Vt, 8192, nullptr, out, 2048, 4096,
      (size_t)4096 * 4096, (size_t)4096, (size_t)4096 * 2048);
}

// Round 3
// 505.103 us; speedup vs baseline: 1.4610x; 1.0101x over previous
//
#include <hip/hip_runtime.h>
#include <hip/hip_bf16.h>
#include <cstdint>
#include <cstddef>

// ---------------------------------------------------------------------------
// SelfAttention (B=2, S=4096, H=2048, fp32 in/out), fp16 MFMA internally.
// Round 3: same 256x256 8-phase template as round 2, but stage placement
// re-derived for maximum race-free prefetch depth with 2 LDS buffers:
//   - A regions of a buffer die at phase 3 (last LOAD_A) -> stage next A
//     pair at ph4/ph8 (2 stages, 4 loads)
//   - B regions die at phase 4 -> stage next B pair at ph1/ph5
//   - waits become vmcnt(4) at ph4/ph8; every staged load has 3-4 phases
//     (~500+ cyc) in flight before its wait (round 2 gave the ph3-issued
//     load only ~1 phase -> latency stall at every K-tile boundary)
// ---------------------------------------------------------------------------

typedef _Float16 half8 __attribute__((ext_vector_type(8)));
typedef _Float16 half4 __attribute__((ext_vector_type(4)));
typedef float    f32x4 __attribute__((ext_vector_type(4)));

__device__ __forceinline__ void gld_lds16(const void* g, void* l) {
  __builtin_amdgcn_global_load_lds(
      (const __attribute__((address_space(1))) unsigned int*)g,
      (__attribute__((address_space(3))) unsigned int*)l, 16, 0, 0);
}

#define FENCE()  asm volatile("" ::: "memory")
#define LGKM(n)  asm volatile("s_waitcnt lgkmcnt(" #n ")" ::: "memory")
#define VMC(n)   asm volatile("s_waitcnt vmcnt(" #n ")" ::: "memory")
#define SBAR()   do { __builtin_amdgcn_s_barrier(); FENCE(); } while (0)
#define SCHED0() __builtin_amdgcn_sched_barrier(0)
#define PRIO1()  __builtin_amdgcn_s_setprio(1)
#define PRIO0()  __builtin_amdgcn_s_setprio(0)

// ds-load one A register subtile (4 m-frags x 2 k-slices = 8 x ds_read_b128)
#define LOAD_A(bsel, mh)                                                     \
  {                                                                          \
    const char* _p = ldsA + ((bsel)*2 + wr) * 16384 + fr * 128;              \
    _Pragma("unroll") for (int mi = 0; mi < 4; ++mi) {                       \
      af[mi][0] = *(const half8*)(_p + ((mh)*4 + mi) * 2048 + cS0);          \
      af[mi][1] = *(const half8*)(_p + ((mh)*4 + mi) * 2048 + cS1);          \
    }                                                                        \
  }

// ds-load one B register subtile (2 n-frags x 2 k-slices = 4 x ds_read_b128)
#define LOAD_B(bsel, nh)                                                     \
  {                                                                          \
    const char* _p = ldsB + ((bsel)*2 + (wc >> 1)) * 16384 +                 \
                     ((wc & 1) * 64 + fr) * 128;                             \
    _Pragma("unroll") for (int ni = 0; ni < 2; ++ni) {                       \
      bf[ni][0] = *(const half8*)(_p + ((nh)*2 + ni) * 2048 + cS0);          \
      bf[ni][1] = *(const half8*)(_p + ((nh)*2 + ni) * 2048 + cS1);          \
    }                                                                        \
  }

// one C-quadrant x K=64: 16 MFMA
#define MFMA_Q(mh, nh)                                                       \
  _Pragma("unroll") for (int mi = 0; mi < 4; ++mi)                           \
  _Pragma("unroll") for (int ni = 0; ni < 2; ++ni) {                         \
    f32x4& _c = acc[(mh)*4 + mi][(nh)*2 + ni];                               \
    _c = __builtin_amdgcn_mfma_f32_16x16x32_f16(af[mi][0], bf[ni][0], _c, 0, 0, 0); \
    _c = __builtin_amdgcn_mfma_f32_16x16x32_f16(af[mi][1], bf[ni][1], _c, 0, 0, 0); \
  }

// stage one 128x64 half-tile (16KB): per wave 2 x global_load_lds(16B).
// LDS dest linear; global source column pre-swizzled (involution) so reads
// with cb ^ ((row&7)<<4) land correctly (both-sides rule, m173/m201).
#define STAGE_A(bsel, h, t)                                                  \
  {                                                                          \
    const _Float16* _s = A + (size_t)(bm + (h)*128 + wv*16 + lr) * lda +     \
                         (size_t)(t) * 64 + sc8;                             \
    char* _d = ldsA + ((bsel)*2 + (h)) * 16384 + wv * 2048;                  \
    gld_lds16(_s, _d);                                                       \
    gld_lds16(_s + ((size_t)lda << 3), _d + 1024);                           \
  }
#define STAGE_B(bsel, h, t)                                                  \
  {                                                                          \
    const _Float16* _s = B + (size_t)(bn + (h)*128 + wv*16 + lr) * ldb +     \
                         (size_t)(t) * 64 + sc8;                             \
    char* _d = ldsB + ((bsel)*2 + (h)) * 16384 + wv * 2048;                  \
    gld_lds16(_s, _d);                                                       \
    gld_lds16(_s + ((size_t)ldb << 3), _d + 1024);                           \
  }

// MODE 0: fp32 row-major out, no bias   (scores, final out)
// MODE 1: fp16 row-major out + bias     (Q, K projections)
// MODE 2: fp16 TRANSPOSED out + bias    (V projection -> Vt[col*ldo + row])
template <int MODE>
__global__ __launch_bounds__(512) void gemm256(
    const _Float16* __restrict__ A, int lda,
    const _Float16* __restrict__ B, int ldb,
    const float* __restrict__ bias,
    void* __restrict__ out, int ldo, int K,
    size_t sA, size_t sB, size_t sO)
{
  __shared__ __attribute__((aligned(128))) char lds[131072];
  char* ldsA = lds;            // [dbuf*2+half][16KB]
  char* ldsB = lds + 65536;

  const int tid  = threadIdx.x;
  const int wv   = tid >> 6;        // 0..7
  const int lane = tid & 63;
  const int wr = wv >> 2;           // 0..1: wave row  (M, 128 rows each)
  const int wc = wv & 3;            // 0..3: wave col  (N, 64 cols each)
  const int bm = blockIdx.x * 256;
  const int bn = blockIdx.y * 256;
  A += (size_t)blockIdx.z * sA;
  B += (size_t)blockIdx.z * sB;

  // fragment-read indexing
  const int fr = lane & 15;                 // frag row (A) / col (B)
  const int kq = lane >> 4;                 // k-quarter 0..3
  const int sx = (fr & 7) << 4;             // swizzle XOR (bytes 4..6)
  const int cS0 = (kq * 16) ^ sx;           // ks=0 column bytes, swizzled
  const int cS1 = (64 + kq * 16) ^ sx;      // ks=1
  // staging indexing
  const int lr  = lane >> 3;                          // 0..7: row in 8-row chunk
  const int sc8 = ((lane & 7) ^ (lr & 7)) << 3;       // src col (halfs), pre-swz

  f32x4 acc[8][4];
  const f32x4 zf = {0.f, 0.f, 0.f, 0.f};
#pragma unroll
  for (int mi = 0; mi < 8; ++mi)
#pragma unroll
    for (int ni = 0; ni < 4; ++ni) acc[mi][ni] = zf;
  half8 af[4][2], bf[2][2];

  const int NT = K >> 6;      // 64-wide K-tiles (even here: 32 or 64)
  const int NI = NT >> 1;

  // prologue: tile0 fully (8 loads) + A pair of tile1 (4 loads)
  STAGE_A(0, 0, 0); STAGE_A(0, 1, 0); STAGE_B(0, 0, 0); STAGE_B(0, 1, 0);
  STAGE_A(1, 0, 1); STAGE_A(1, 1, 1);
  VMC(4);   // tile0's 8 loads done; tile1's A pair still in flight
  SBAR();

  for (int it = 0; it < NI; ++it) {
    const int t1 = 2 * it + 1, t2 = t1 + 1, t3 = t1 + 2;
    const bool more = (t2 < NT);           // NT even => t3 < NT iff t2 < NT

    // ===== group 1: buf0, K-tile 2it =====
    // ph1 (mh0,nh0) — stage B pair of t1 (buf1 B free since prev ph8)
    LOAD_A(0, 0); LOAD_B(0, 0);
    STAGE_B(1, 0, t1); STAGE_B(1, 1, t1);
    LGKM(8);
    SBAR(); LGKM(0); SCHED0();
    PRIO1(); MFMA_Q(0, 0); PRIO0();
    SBAR();
    // ph2 (mh0,nh1)
    LOAD_B(0, 1);
    SBAR(); LGKM(0); SCHED0();
    PRIO1(); MFMA_Q(0, 1); PRIO0();
    SBAR();
    // ph3 (mh1,nh1) — last A read of buf0
    LOAD_A(0, 1);
    SBAR(); LGKM(0); SCHED0();
    PRIO1(); MFMA_Q(1, 1); PRIO0();
    SBAR();
    // ph4 (mh1,nh0) — stage A pair of t2 (buf0 A now dead)
    LOAD_B(0, 0);
    if (more) { STAGE_A(0, 0, t2); STAGE_A(0, 1, t2); }
    SBAR(); LGKM(0); SCHED0();
    PRIO1(); MFMA_Q(1, 0); PRIO0();
    if (more) { VMC(4); } else { VMC(0); }   // t1 (buf1) fully staged
    SBAR();

    // ===== group 2: buf1, K-tile 2it+1 =====
    // ph5 (mh0,nh0) — stage B pair of t2 (buf0 B dead after ph4)
    LOAD_A(1, 0); LOAD_B(1, 0);
    if (more) { STAGE_B(0, 0, t2); STAGE_B(0, 1, t2); }
    LGKM(8);
    SBAR(); LGKM(0); SCHED0();
    PRIO1(); MFMA_Q(0, 0); PRIO0();
    SBAR();
    // ph6 (mh0,nh1)
    LOAD_B(1, 1);
    SBAR(); LGKM(0); SCHED0();
    PRIO1(); MFMA_Q(0, 1); PRIO0();
    SBAR();
    // ph7 (mh1,nh1) — last A read of buf1
    LOAD_A(1, 1);
    SBAR(); LGKM(0); SCHED0();
    PRIO1(); MFMA_Q(1, 1); PRIO0();
    SBAR();
    // ph8 (mh1,nh0) — stage A pair of t3 (buf1 A now dead)
    LOAD_B(1, 0);
    if (more) { STAGE_A(1, 0, t3); STAGE_A(1, 1, t3); }
    SBAR(); LGKM(0); SCHED0();
    PRIO1(); MFMA_Q(1, 0); PRIO0();
    if (more) { VMC(4); SBAR(); }            // t2 (buf0) fully staged
  }

  // epilogue. C/D frag: col = lane&15, rows = (lane>>4)*4 + j
#pragma unroll
  for (int mi = 0; mi < 8; ++mi) {
#pragma unroll
    for (int ni = 0; ni < 4; ++ni) {
      const int col  = bn + wc * 64 + ni * 16 + fr;
      const int row0 = bm + wr * 128 + mi * 16 + kq * 4;
      const f32x4 a = acc[mi][ni];
      if constexpr (MODE == 0) {
        float* O = (float*)out + (size_t)blockIdx.z * sO;
#pragma unroll
        for (int j = 0; j < 4; ++j) O[(size_t)(row0 + j) * ldo + col] = a[j];
      } else if constexpr (MODE == 1) {
        _Float16* O = (_Float16*)out;
        const float bb = bias[col];
#pragma unroll
        for (int j = 0; j < 4; ++j)
          O[(size_t)(row0 + j) * ldo + col] = (_Float16)(a[j] + bb);
      } else {
        _Float16* O = (_Float16*)out;
        const float bb = bias[col];
        half4 h;
#pragma unroll
        for (int j = 0; j < 4; ++j) h[j] = (_Float16)(a[j] + bb);
        *(half4*)(O + (size_t)col * ldo + row0) = h;
      }
    }
  }
}

__device__ __forceinline__ float wave_max_f(float v) {
#pragma unroll
  for (int o = 32; o; o >>= 1) v = fmaxf(v, __shfl_xor(v, o));
  return v;
}
__device__ __forceinline__ float wave_sum_f(float v) {
#pragma unroll
  for (int o = 32; o; o >>= 1) v += __shfl_xor(v, o);
  return v;
}

// one 256-thread block per row of 4096 fp32 scores -> fp16 probabilities
__global__ __launch_bounds__(256) void softmax_rows(
    const float* __restrict__ S, _Float16* __restrict__ P)
{
  __shared__ float rmax[4], rsum[4];
  const int tid = threadIdx.x;
  const float* s = S + (size_t)blockIdx.x * 4096;
  _Float16*    p = P + (size_t)blockIdx.x * 4096;

  f32x4 v[4];
  float m = -3.0e38f;
#pragma unroll
  for (int i = 0; i < 4; ++i) {
    v[i] = ((const f32x4*)s)[i * 256 + tid];
#pragma unroll
    for (int j = 0; j < 4; ++j) m = fmaxf(m, v[i][j]);
  }
  m = wave_max_f(m);
  if ((tid & 63) == 0) rmax[tid >> 6] = m;
  __syncthreads();
  m = fmaxf(fmaxf(rmax[0], rmax[1]), fmaxf(rmax[2], rmax[3]));

  float e[16];
  float sum = 0.f;
#pragma unroll
  for (int i = 0; i < 4; ++i)
#pragma unroll
    for (int j = 0; j < 4; ++j) {
      const float t = __expf(v[i][j] - m);
      e[i * 4 + j] = t;
      sum += t;
    }
  sum = wave_sum_f(sum);
  if ((tid & 63) == 0) rsum[tid >> 6] = sum;
  __syncthreads();
  sum = rsum[0] + rsum[1] + rsum[2] + rsum[3];
  const float inv = 1.0f / sum;

#pragma unroll
  for (int i = 0; i < 4; ++i) {
    half4 h;
#pragma unroll
    for (int j = 0; j < 4; ++j) h[j] = (_Float16)(e[i * 4 + j] * inv);
    ((half4*)p)[i * 256 + tid] = h;
  }
}

__global__ __launch_bounds__(256) void cvt_f32_f16(
    const float* __restrict__ in, _Float16* __restrict__ out, int n4)
{
  const int stride = gridDim.x * 256;
  for (int idx = blockIdx.x * 256 + threadIdx.x; idx < n4; idx += stride) {
    const f32x4 x = ((const f32x4*)in)[idx];
    half4 h;
#pragma unroll
    for (int j = 0; j < 4; ++j) h[j] = (_Float16)x[j];
    ((half4*)out)[idx] = h;
  }
}

extern "C" void kernel_launch(void* const* d_in, const int* in_sizes, int n_in,
                              void* d_out, int out_size, void* d_ws, size_t ws_size,
                              hipStream_t stream)
{
  const float* X  = (const float*)d_in[0];
  const float* Wq = (const float*)d_in[1];
  const float* bq = (const float*)d_in[2];
  const float* Wk = (const float*)d_in[3];
  const float* bk = (const float*)d_in[4];
  const float* Wv = (const float*)d_in[5];
  const float* bv = (const float*)d_in[6];
  float* out = (float*)d_out;

  const size_t NX = (size_t)2 * 4096 * 2048;  // 16,777,216
  const size_t NW = (size_t)2048 * 2048;      //  4,194,304
  const size_t NS = (size_t)2 * 4096 * 4096;  // 33,554,432

  // Workspace layout (lifetime-aliased, total ~235 MB):
  //  [0, 134.2MB)        : S fp32  — also hosts Xh + W*h fp16 during stages 1-2
  //  [134.2MB, 201.3MB)  : Q | Kp fp16 — later aliased by P fp16
  //  [201.3MB, 234.9MB)  : Vt fp16 [2048][8192]
  char* w = (char*)d_ws;
  float*    Ssc = (float*)w;
  _Float16* Xh  = (_Float16*)w;
  _Float16* Wqh = (_Float16*)(w + NX * 2);
  _Float16* Wkh = (_Float16*)(w + NX * 2 + NW * 2);
  _Float16* Wvh = (_Float16*)(w + NX * 2 + 2 * NW * 2);
  _Float16* Q   = (_Float16*)(w + NS * 4);
  _Float16* Kp  = (_Float16*)(w + NS * 4 + NX * 2);
  _Float16* P   = (_Float16*)(w + NS * 4);            // aliases Q+Kp
  _Float16* Vt  = (_Float16*)(w + NS * 4 + 2 * NX * 2);

  // 1) fp32 -> fp16 conversions
  cvt_f32_f16<<<2048, 256, 0, stream>>>(X,  Xh,  (int)(NX / 4));
  cvt_f32_f16<<<512,  256, 0, stream>>>(Wq, Wqh, (int)(NW / 4));
  cvt_f32_f16<<<512,  256, 0, stream>>>(Wk, Wkh, (int)(NW / 4));
  cvt_f32_f16<<<512,  256, 0, stream>>>(Wv, Wvh, (int)(NW / 4));

  const dim3 blk(512);
  // 2) projections: [8192,2048] = Xh[8192,2048] @ W[2048,2048]^T + b
  gemm256<1><<<dim3(32, 8, 1), blk, 0, stream>>>(Xh, 2048, Wqh, 2048, bq,
                                                 Q, 2048, 2048, 0, 0, 0);
  gemm256<1><<<dim3(32, 8, 1), blk, 0, stream>>>(Xh, 2048, Wkh, 2048, bk,
                                                 Kp, 2048, 2048, 0, 0, 0);
  gemm256<2><<<dim3(32, 8, 1), blk, 0, stream>>>(Xh, 2048, Wvh, 2048, bv,
                                                 Vt, 8192, 2048, 0, 0, 0);
  // 3) scores: per batch, S[4096,4096] = Q K^T (fp32 out)
  gemm256<0><<<dim3(16, 16, 2), blk, 0, stream>>>(
      Q, 2048, Kp, 2048, nullptr, Ssc, 4096, 2048,
      (size_t)4096 * 2048, (size_t)4096 * 2048, (size_t)4096 * 4096);
  // 4) row softmax (8192 rows), fp32 -> fp16 probs
  softmax_rows<<<8192, 256, 0, stream>>>(Ssc, P);
  // 5) out: per batch, [4096,2048] = P[4096,4096] @ Vt^T (Vt rows = h)
  gemm256<0><<<dim3(16, 8, 2), blk, 0, stream>>>(
      P, 4096, Vt, 8192, nullptr, out, 2048, 4096,
      (size_t)4096 * 4096, (size_t)4096, (size_t)4096 * 2048);
}